// Round 5
// baseline (2150631.836 us; speedup 1.0000x reference)
//
#include <hip/hip_runtime.h>
#include <math.h>

#define AGENT __HIP_MEMORY_SCOPE_AGENT
typedef unsigned long long u64;
typedef unsigned int uv4 __attribute__((ext_vector_type(4)));

__device__ __forceinline__ float sigf(float x) { return 1.f / (1.f + __expf(-x)); }
__device__ __forceinline__ float tanh_fast(float x) { return 1.f - 2.f / (__expf(2.f * x) + 1.f); }
__device__ __forceinline__ float lrelu(float x) { return x > 0.f ? x : 0.01f * x; }
__device__ __forceinline__ u64 aload64(const u64* p) {
    return __hip_atomic_load(p, __ATOMIC_RELAXED, AGENT);
}
__device__ __forceinline__ void astore64(u64* p, u64 v) {
    __hip_atomic_store(p, v, __ATOMIC_RELAXED, AGENT);
}
__device__ __forceinline__ int aloadi(const int* p) {
    return __hip_atomic_load(p, __ATOMIC_RELAXED, AGENT);
}
__device__ __forceinline__ void astorei(int* p, int v) {
    __hip_atomic_store(p, v, __ATOMIC_RELAXED, AGENT);
}

struct Ctrl {
    int first, target, roleCtr, open, mode, pad0, pad1, pad2;
    int xcds[96];
};

// ---------------- generic fp32 GEMM: C[m][n] = sum_k A[m][k]*B[n][k] + bias ----
template <bool LRELU>
__global__ __launch_bounds__(256) void gemm_bias(
    const float* __restrict__ A, const float* __restrict__ B,
    const float* __restrict__ bias1, const float* __restrict__ bias2,
    float* __restrict__ C, int M, int N, int K)
{
    __shared__ float As[16][68];
    __shared__ float Bs[16][68];
    const int tid = threadIdx.x;
    const int m0 = blockIdx.y * 64, n0 = blockIdx.x * 64;
    const int tm = tid >> 4, tn = tid & 15;
    const int lr = tid >> 2;
    const int lk = (tid & 3) * 4;
    float acc[4][4] = {};
    for (int k0 = 0; k0 < K; k0 += 16) {
        float4 av = make_float4(0.f, 0.f, 0.f, 0.f);
        if (m0 + lr < M) av = *(const float4*)&A[(size_t)(m0 + lr) * K + k0 + lk];
        As[lk + 0][lr] = av.x; As[lk + 1][lr] = av.y;
        As[lk + 2][lr] = av.z; As[lk + 3][lr] = av.w;
        float4 bv = make_float4(0.f, 0.f, 0.f, 0.f);
        if (n0 + lr < N) bv = *(const float4*)&B[(size_t)(n0 + lr) * K + k0 + lk];
        Bs[lk + 0][lr] = bv.x; Bs[lk + 1][lr] = bv.y;
        Bs[lk + 2][lr] = bv.z; Bs[lk + 3][lr] = bv.w;
        __syncthreads();
#pragma unroll
        for (int kk = 0; kk < 16; kk++) {
            float a[4], b[4];
#pragma unroll
            for (int i = 0; i < 4; i++) a[i] = As[kk][tm * 4 + i];
#pragma unroll
            for (int j = 0; j < 4; j++) b[j] = Bs[kk][tn * 4 + j];
#pragma unroll
            for (int i = 0; i < 4; i++)
#pragma unroll
                for (int j = 0; j < 4; j++) acc[i][j] += a[i] * b[j];
        }
        __syncthreads();
    }
#pragma unroll
    for (int i = 0; i < 4; i++) {
#pragma unroll
        for (int j = 0; j < 4; j++) {
            int mm = m0 + tm * 4 + i, nn = n0 + tn * 4 + j;
            if (mm < M && nn < N) {
                float v = acc[i][j];
                if (bias1) v += bias1[nn];
                if (bias2) v += bias2[nn];
                if (LRELU) v = lrelu(v);
                C[(size_t)mm * N + nn] = v;
            }
        }
    }
}

// ---------------- persistent pipelined LSTM1+LSTM2 scan ------------------------
// Tagged-data sync. mode==2: all 96 role-WGs verified on ONE XCD -> publishes are
// plain dwordx2 stores (write-through L1 into the shared per-XCD L2) and polls
// are sc0 loads (L1 bypass, L2 serviced) => ~4x lower hop latency than agent
// scope. mode==1 fallback: agent-scope ops (R3 behavior). Producers dual-store
// (plain + agent) so sc0 polls can always fall back to agent loads safely.
__global__ __launch_bounds__(256) void lstm_pipe(
    const float* __restrict__ gx1, const float* __restrict__ Whh1,
    const float* __restrict__ Wih2, const float* __restrict__ Whh2,
    const float* __restrict__ bih2, const float* __restrict__ bhh2,
    u64* __restrict__ h1pub, u64* __restrict__ h2pub,
    float* __restrict__ h2seq, Ctrl* __restrict__ ctrl,
    u64* __restrict__ zerobuf)
{
    const int tid = threadIdx.x;
    __shared__ int sh_role, sh_mode, sh_first;

    // ---------------- XCD election ----------------
    if (tid == 0) {
        unsigned xcd;
        asm volatile("s_getreg_b32 %0, hwreg(HW_REG_XCC_ID)" : "=s"(xcd));
        xcd &= 15;
        int first = __hip_atomic_fetch_add(&ctrl->first, 1, __ATOMIC_RELAXED, AGENT);
        if (first == 0) astorei(&ctrl->target, (int)xcd | 256);
        int tgt;
        while (((tgt = aloadi(&ctrl->target)) & 256) == 0) {}
        tgt &= 255;
        u64 t0 = __builtin_amdgcn_s_memrealtime();
        int role = -1;
        if ((int)xcd == tgt) {
            role = __hip_atomic_fetch_add(&ctrl->roleCtr, 1, __ATOMIC_RELAXED, AGENT);
        } else {
            for (;;) {
                if (aloadi(&ctrl->roleCtr) >= 96) break;
                if (aloadi(&ctrl->open)) {
                    role = __hip_atomic_fetch_add(&ctrl->roleCtr, 1, __ATOMIC_RELAXED, AGENT);
                    break;
                }
            }
        }
        if (role >= 96) role = -1;
        if (role >= 0) astorei(&ctrl->xcds[role], (int)xcd + 1);
        if (first == 0) {
            // monitor fill; open claiming to any XCD on timeout (fallback)
            while (aloadi(&ctrl->roleCtr) < 96) {
                if (__builtin_amdgcn_s_memrealtime() - t0 > 200000ull)
                    astorei(&ctrl->open, 1);
            }
        }
        sh_role = role; sh_first = first;
    }
    __syncthreads();
    {
        const int role_ = sh_role, first_ = sh_first;
        if (first_ == 0 && tid < 64) {
            // leader WG: wave 0 gathers all claimed XCDs, publishes mode
            int v0 = 0;
            if (tid == 0) { while ((v0 = aloadi(&ctrl->xcds[0])) == 0) {} }
            int ref = __shfl(v0, 0, 64);
            int a;
            while ((a = aloadi(&ctrl->xcds[tid])) == 0) {}
            bool ok = (a == ref);
            if (64 + tid < 96) {
                int b;
                while ((b = aloadi(&ctrl->xcds[64 + tid])) == 0) {}
                ok = ok && (b == ref);
            }
            int same = __all(ok);
            if (tid == 0) astorei(&ctrl->mode, same ? 2 : 1);
        }
        if (role_ < 0 && first_ != 0) return;  // WG-uniform
        if (tid == 0) {
            int m;
            while ((m = aloadi(&ctrl->mode)) == 0) {}
            sh_mode = m;
        }
        __syncthreads();
        if (sh_role < 0) return;
    }
    const int wg = sh_role;
    const int mode = sh_mode;

    const int r = tid & 31, p = tid >> 5;
    __shared__ float xl[512];
    __shared__ float hl[256];
    __shared__ float part[8][32];

    if (wg < 64) {
        // ---------------- LSTM1: H=512, owns h[jb..jb+8) ----------------
        const int jb = wg * 8;
        const int grow = (r >> 3) * 512 + jb + (r & 7);
        float w[64];
#pragma unroll
        for (int q = 0; q < 64; q++) w[q] = Whh1[(size_t)grow * 512 + p * 64 + q];
        float cstate = 0.f;  // live in wave-0 lanes < 8

        for (int t = 0; t < 4096; ++t) {
            // prefetch gx for this step's 32 gate rows (independent of poll)
            float gxv = 0.f;
            if (tid < 32) gxv = gx1[(size_t)t * 2048 + (tid >> 3) * 512 + jb + (tid & 7)];
            // poll h(t-1): 2 tagged words per thread (one 16B load)
            float fa = 0.f, fb = 0.f;
            {
                const u64* p1 = (t > 0) ? (h1pub + (size_t)(t - 1) * 512 + 2 * tid)
                                        : (zerobuf + 2 * tid);
                const unsigned want = (unsigned)t;
                if (mode == 2) {
                    uv4 v; int spins = 0;
                    for (;;) {
                        asm volatile("global_load_dwordx4 %0, %1, off sc0\n\t"
                                     "s_waitcnt vmcnt(0)"
                                     : "=&v"(v) : "v"(p1) : "memory");
                        if (__all((v.y == want) & (v.w == want))) break;
                        if (++spins > 4096) {  // safety: agent fallback
                            u64 a = aload64(p1), b = aload64(p1 + 1);
                            while (!__all(((unsigned)(a >> 32) == want) &
                                          ((unsigned)(b >> 32) == want))) {
                                a = aload64(p1); b = aload64(p1 + 1);
                            }
                            v.x = (unsigned)a; v.z = (unsigned)b;
                            break;
                        }
                    }
                    fa = __uint_as_float(v.x); fb = __uint_as_float(v.z);
                } else if (t > 0) {
                    u64 a = aload64(p1), b = aload64(p1 + 1);
                    while (!__all(((unsigned)(a >> 32) == want) &
                                  ((unsigned)(b >> 32) == want))) {
                        if ((unsigned)(a >> 32) != want) a = aload64(p1);
                        if ((unsigned)(b >> 32) != want) b = aload64(p1 + 1);
                    }
                    fa = __uint_as_float((unsigned)a);
                    fb = __uint_as_float((unsigned)b);
                }
            }
            xl[2 * tid] = fa; xl[2 * tid + 1] = fb;
            __syncthreads();  // B1: xl ready
            float acc = 0.f;
#pragma unroll
            for (int q = 0; q < 64; q++) acc += w[q] * xl[p * 64 + q];
            part[p][r] = acc;
            __syncthreads();  // B2: partials ready
            if (tid < 32) {
                float s = gxv;
#pragma unroll
                for (int pp = 0; pp < 8; pp++) s += part[pp][tid];
                float act = ((tid >> 3) == 2) ? tanh_fast(s) : sigf(s);
                const int e = tid & 7;
                float vi = __shfl(act, e, 64);
                float vf = __shfl(act, e + 8, 64);
                float vg = __shfl(act, e + 16, 64);
                float vo = __shfl(act, e + 24, 64);
                if (tid < 8) {
                    float c = vf * cstate + vi * vg;
                    cstate = c;
                    float h = vo * tanh_fast(c);
                    u64* pp_ = h1pub + (size_t)t * 512 + jb + tid;
                    u64 pv = ((u64)(t + 1) << 32) | (u64)__float_as_uint(h);
                    if (mode == 2)
                        asm volatile("global_store_dwordx2 %0, %1, off"
                                     :: "v"(pp_), "v"(pv) : "memory");
                    astore64(pp_, pv);
                }
            }
        }
    } else {
        // ---------------- LSTM2: H=256, pipelined 1 step behind ----------------
        const int k = wg - 64, jb = k * 8;
        const int grow = (r >> 3) * 256 + jb + (r & 7);
        float wi[64], wh[32];
#pragma unroll
        for (int q = 0; q < 64; q++) wi[q] = Wih2[(size_t)grow * 512 + p * 64 + q];
#pragma unroll
        for (int q = 0; q < 32; q++) wh[q] = Whh2[(size_t)grow * 256 + p * 32 + q];
        float bs = 0.f;
        if (tid < 32) {
            int row = (tid >> 3) * 256 + jb + (tid & 7);
            bs = bih2[row] + bhh2[row];
        }
        float cstate = 0.f;

        for (int t = 0; t < 4096; ++t) {
            {
                const u64* p1 = h1pub + (size_t)t * 512 + 2 * tid;
                const u64* p2 = (t > 0) ? (h2pub + (size_t)(t - 1) * 256 + tid)
                                        : (zerobuf + tid);
                const unsigned w1 = (unsigned)(t + 1), w2 = (unsigned)t;
                float fa, fb, hv;
                if (mode == 2) {
                    uv4 v; u64 c; int spins = 0;
                    for (;;) {
                        asm volatile("global_load_dwordx4 %0, %2, off sc0\n\t"
                                     "global_load_dwordx2 %1, %3, off sc0\n\t"
                                     "s_waitcnt vmcnt(0)"
                                     : "=&v"(v), "=&v"(c) : "v"(p1), "v"(p2) : "memory");
                        if (__all((v.y == w1) & (v.w == w1) &
                                  ((unsigned)(c >> 32) == w2))) break;
                        if (++spins > 4096) {  // safety: agent fallback
                            u64 a = aload64(p1), b = aload64(p1 + 1), cc = aload64(p2);
                            while (!__all(((unsigned)(a >> 32) == w1) &
                                          ((unsigned)(b >> 32) == w1) &
                                          ((unsigned)(cc >> 32) == w2))) {
                                a = aload64(p1); b = aload64(p1 + 1); cc = aload64(p2);
                            }
                            v.x = (unsigned)a; v.z = (unsigned)b; c = cc;
                            break;
                        }
                    }
                    fa = __uint_as_float(v.x); fb = __uint_as_float(v.z);
                    hv = __uint_as_float((unsigned)c);
                } else {
                    u64 a = aload64(p1), b = aload64(p1 + 1);
                    u64 c = (t > 0) ? aload64(p2) : ((u64)w2 << 32);
                    while (!__all(((unsigned)(a >> 32) == w1) &
                                  ((unsigned)(b >> 32) == w1) &
                                  ((unsigned)(c >> 32) == w2))) {
                        if ((unsigned)(a >> 32) != w1) a = aload64(p1);
                        if ((unsigned)(b >> 32) != w1) b = aload64(p1 + 1);
                        if ((unsigned)(c >> 32) != w2) c = aload64(p2);
                    }
                    fa = __uint_as_float((unsigned)a);
                    fb = __uint_as_float((unsigned)b);
                    hv = (t > 0) ? __uint_as_float((unsigned)c) : 0.f;
                }
                xl[2 * tid] = lrelu(fa);
                xl[2 * tid + 1] = lrelu(fb);
                hl[tid] = hv;
            }
            __syncthreads();  // B1
            float acc = 0.f;
#pragma unroll
            for (int q = 0; q < 64; q++) acc += wi[q] * xl[p * 64 + q];
#pragma unroll
            for (int q = 0; q < 32; q++) acc += wh[q] * hl[p * 32 + q];
            part[p][r] = acc;
            __syncthreads();  // B2
            if (tid < 32) {
                float s = bs;
#pragma unroll
                for (int pp = 0; pp < 8; pp++) s += part[pp][tid];
                float act = ((tid >> 3) == 2) ? tanh_fast(s) : sigf(s);
                const int e = tid & 7;
                float vi = __shfl(act, e, 64);
                float vf = __shfl(act, e + 8, 64);
                float vg = __shfl(act, e + 16, 64);
                float vo = __shfl(act, e + 24, 64);
                if (tid < 8) {
                    float c = vf * cstate + vi * vg;
                    cstate = c;
                    float h = vo * tanh_fast(c);
                    u64* pp_ = h2pub + (size_t)t * 256 + jb + tid;
                    u64 pv = ((u64)(t + 1) << 32) | (u64)__float_as_uint(h);
                    if (mode == 2)
                        asm volatile("global_store_dwordx2 %0, %1, off"
                                     :: "v"(pp_), "v"(pv) : "memory");
                    astore64(pp_, pv);
                    h2seq[(size_t)t * 256 + jb + tid] = lrelu(h);
                }
            }
        }
    }
}

// ---------------- GCN edge scatter: y[dst] += ew * m[src] ----------------------
__global__ void gcn_scatter(const float* __restrict__ m, const int* __restrict__ ei,
                            const float* __restrict__ ew, float* __restrict__ y,
                            int shift, int nE)
{
    int idx = blockIdx.x * 256 + threadIdx.x;
    int e = idx >> shift;
    if (e >= nE) return;
    int C = 1 << shift;
    int ch = idx & (C - 1);
    int s = ei[e], d = ei[nE + e];
    atomicAdd(&y[(size_t)d * C + ch], ew[e] * m[(size_t)s * C + ch]);
}

// ---------------- BN (training-mode batch stats) -------------------------------
__global__ __launch_bounds__(256) void bn_stats(
    const float* __restrict__ x, const float* __restrict__ gamma,
    const float* __restrict__ beta, float* __restrict__ scale,
    float* __restrict__ shift, int Nn, int C)
{
    int ch = blockIdx.x;
    float s = 0.f, s2 = 0.f;
    for (int n = threadIdx.x; n < Nn; n += 256) {
        float v = x[(size_t)n * C + ch];
        s += v; s2 += v * v;
    }
    __shared__ float rs[256], rq[256];
    rs[threadIdx.x] = s; rq[threadIdx.x] = s2;
    __syncthreads();
    for (int o = 128; o > 0; o >>= 1) {
        if (threadIdx.x < o) {
            rs[threadIdx.x] += rs[threadIdx.x + o];
            rq[threadIdx.x] += rq[threadIdx.x + o];
        }
        __syncthreads();
    }
    if (threadIdx.x == 0) {
        float mean = rs[0] / Nn;
        float var = rq[0] / Nn - mean * mean;
        float inv = rsqrtf(var + 1e-5f);
        float sc = gamma[ch] * inv;
        scale[ch] = sc;
        shift[ch] = beta[ch] - mean * sc;
    }
}

__global__ void bn_apply(const float* __restrict__ x, const float* __restrict__ scale,
                         const float* __restrict__ shift, float* __restrict__ z,
                         int mask, int total)
{
    int idx = blockIdx.x * 256 + threadIdx.x;
    if (idx >= total) return;
    int ch = idx & mask;
    z[idx] = lrelu(x[idx] * scale[ch] + shift[ch]);
}

// ---------------- global_add_pool via batch array ------------------------------
__global__ void pool_kernel(const float* __restrict__ z, const int* __restrict__ batch,
                            float* __restrict__ pooled, int total)
{
    int idx = blockIdx.x * 256 + threadIdx.x;
    if (idx >= total) return;
    int n = idx >> 5, ch = idx & 31;
    atomicAdd(&pooled[(size_t)batch[n] * 32 + ch], z[idx]);
}

// ---------------- final tiny MLP: 32 -> 16 -> 8 -> 2, one thread per graph -----
__global__ void mlp_kernel(const float* __restrict__ pooled,
                           const float* __restrict__ w2, const float* __restrict__ b2,
                           const float* __restrict__ w3, const float* __restrict__ b3,
                           const float* __restrict__ w4, const float* __restrict__ b4,
                           float* __restrict__ out)
{
    int g = blockIdx.x * 256 + threadIdx.x;
    if (g >= 512) return;
    float pbuf[32];
#pragma unroll
    for (int i = 0; i < 32; i++) pbuf[i] = pooled[g * 32 + i];
    float a[16];
#pragma unroll
    for (int j = 0; j < 16; j++) {
        float s = b2[j];
#pragma unroll
        for (int i = 0; i < 32; i++) s += w2[j * 32 + i] * pbuf[i];
        a[j] = lrelu(s);
    }
    float c8[8];
#pragma unroll
    for (int j = 0; j < 8; j++) {
        float s = b3[j];
#pragma unroll
        for (int i = 0; i < 16; i++) s += w3[j * 16 + i] * a[i];
        c8[j] = lrelu(s);
    }
#pragma unroll
    for (int j = 0; j < 2; j++) {
        float s = b4[j];
#pragma unroll
        for (int i = 0; i < 8; i++) s += w4[j * 8 + i] * c8[i];
        out[g * 2 + j] = lrelu(s);
    }
}

extern "C" void kernel_launch(void* const* d_in, const int* in_sizes, int n_in,
                              void* d_out, int out_size, void* d_ws, size_t ws_size,
                              hipStream_t stream)
{
    (void)in_sizes; (void)n_in; (void)out_size; (void)ws_size;
    const float* x      = (const float*)d_in[0];
    const int*   ei     = (const int*)d_in[1];
    const float* ew     = (const float*)d_in[2];
    const int*   batch  = (const int*)d_in[3];
    const float* W_ih1  = (const float*)d_in[4];
    const float* W_hh1  = (const float*)d_in[5];
    const float* b_ih1  = (const float*)d_in[6];
    const float* b_hh1  = (const float*)d_in[7];
    const float* W_ih2  = (const float*)d_in[8];
    const float* W_hh2  = (const float*)d_in[9];
    const float* b_ih2  = (const float*)d_in[10];
    const float* b_hh2  = (const float*)d_in[11];
    const float* fc1_w  = (const float*)d_in[12];
    const float* fc1_b  = (const float*)d_in[13];
    const float* gcn1_w = (const float*)d_in[14];
    const float* bn1_g  = (const float*)d_in[16];
    const float* bn1_b  = (const float*)d_in[17];
    const float* gcn2_w = (const float*)d_in[18];
    const float* bn2_g  = (const float*)d_in[20];
    const float* bn2_b  = (const float*)d_in[21];
    const float* fc2_w  = (const float*)d_in[22];
    const float* fc2_b  = (const float*)d_in[23];
    const float* fc3_w  = (const float*)d_in[24];
    const float* fc3_b  = (const float*)d_in[25];
    const float* fc4_w  = (const float*)d_in[26];
    const float* fc4_b  = (const float*)d_in[27];
    float* out = (float*)d_out;

    // -------- workspace layout (byte offsets) --------
    char* base = (char*)d_ws;
    const size_t MB = 1024 * 1024;
    float* gx1    = (float*)base;                       // 32MB: 4096*2048 f32
    u64*   h1pub  = (u64*)(base + 32 * MB);             // 16MB: 4096*512 u64
    u64*   h2pub  = (u64*)(base + 48 * MB);             //  8MB: 4096*256 u64
    float* h2seq  = (float*)(base + 56 * MB);           //  4MB: 4096*256 f32
    float* scale1 = (float*)(base + 60 * MB);           // 64
    float* shift1 = scale1 + 64;                        // 64
    float* scale2 = shift1 + 64;                        // 32
    float* shift2 = scale2 + 32;                        // 32
    u64*   zerobuf = (u64*)(base + 60 * MB + 4096);     // 512 u64 (4KB), stays 0
    Ctrl*  ctrl   = (Ctrl*)(base + 60 * MB + 8192);     // election state
    // buffers used only AFTER lstm_pipe — aliased into gx1's space:
    float* h3     = (float*)base;                       // 4096*128
    float* m1     = h3 + (size_t)4096 * 128;            // 4096*64
    float* y1     = m1 + (size_t)4096 * 64;             // 4096*64 (bn in-place)
    float* m2     = y1 + (size_t)4096 * 64;             // 4096*32
    float* y2     = m2 + (size_t)4096 * 32;             // 4096*32 (bn in-place)
    float* pooled = y2 + (size_t)4096 * 32;             // 512*32

    dim3 b256(256);

    // fresh tags + election state every launch (no cross-call state)
    hipMemsetAsync(h1pub, 0, (size_t)4096 * 768 * sizeof(u64), stream);
    hipMemsetAsync(zerobuf, 0, 8192, stream);

    // gx1 = x @ W_ih1^T + (b_ih1 + b_hh1)   [4096,2048]
    gemm_bias<false><<<dim3(2048 / 64, 4096 / 64), b256, 0, stream>>>(
        x, W_ih1, b_ih1, b_hh1, gx1, 4096, 2048, 1280);

    // both LSTM scans, pipelined (96 persistent roles elected from 1024 WGs)
    lstm_pipe<<<1024, b256, 0, stream>>>(gx1, W_hh1, W_ih2, W_hh2, b_ih2, b_hh2,
                                         h1pub, h2pub, h2seq, ctrl, zerobuf);

    // fc1 + lrelu  [4096,128]
    gemm_bias<true><<<dim3(128 / 64, 4096 / 64), b256, 0, stream>>>(
        h2seq, fc1_w, fc1_b, nullptr, h3, 4096, 128, 256);

    // gcn1 linear [4096,64]  (bias cancels in BN)
    gemm_bias<false><<<dim3(1, 4096 / 64), b256, 0, stream>>>(
        h3, gcn1_w, nullptr, nullptr, m1, 4096, 64, 128);
    hipMemsetAsync(y1, 0, (size_t)4096 * 64 * sizeof(float), stream);
    gcn_scatter<<<(32768 * 64) / 256, b256, 0, stream>>>(m1, ei, ew, y1, 6, 32768);
    bn_stats<<<64, b256, 0, stream>>>(y1, bn1_g, bn1_b, scale1, shift1, 4096, 64);
    bn_apply<<<(4096 * 64) / 256, b256, 0, stream>>>(y1, scale1, shift1, y1, 63, 4096 * 64);

    // gcn2 linear [4096,32]
    gemm_bias<false><<<dim3(1, 4096 / 64), b256, 0, stream>>>(
        y1, gcn2_w, nullptr, nullptr, m2, 4096, 32, 64);
    hipMemsetAsync(y2, 0, (size_t)4096 * 32 * sizeof(float), stream);
    gcn_scatter<<<(32768 * 32) / 256, b256, 0, stream>>>(m2, ei, ew, y2, 5, 32768);
    bn_stats<<<32, b256, 0, stream>>>(y2, bn2_g, bn2_b, scale2, shift2, 4096, 32);
    bn_apply<<<(4096 * 32) / 256, b256, 0, stream>>>(y2, scale2, shift2, y2, 31, 4096 * 32);

    // pool + MLP head
    hipMemsetAsync(pooled, 0, (size_t)512 * 32 * sizeof(float), stream);
    pool_kernel<<<(4096 * 32) / 256, b256, 0, stream>>>(y2, batch, pooled, 4096 * 32);
    mlp_kernel<<<2, b256, 0, stream>>>(pooled, fc2_w, fc2_b, fc3_w, fc3_b,
                                       fc4_w, fc4_b, out);
}

// Round 6
// 12590.338 us; speedup vs baseline: 170.8161x; 170.8161x over previous
//
#include <hip/hip_runtime.h>
#include <math.h>

#define AGENT __HIP_MEMORY_SCOPE_AGENT
typedef unsigned long long u64;
typedef unsigned int uv4 __attribute__((ext_vector_type(4)));

__device__ __forceinline__ float sigf(float x) { return 1.f / (1.f + __expf(-x)); }
__device__ __forceinline__ float tanh_fast(float x) { return 1.f - 2.f / (__expf(2.f * x) + 1.f); }
__device__ __forceinline__ float lrelu(float x) { return x > 0.f ? x : 0.01f * x; }
__device__ __forceinline__ u64 aload64(const u64* p) {
    return __hip_atomic_load(p, __ATOMIC_RELAXED, AGENT);
}
__device__ __forceinline__ void astore64(u64* p, u64 v) {
    __hip_atomic_store(p, v, __ATOMIC_RELAXED, AGENT);
}
__device__ __forceinline__ int aloadi(const int* p) {
    return __hip_atomic_load(p, __ATOMIC_RELAXED, AGENT);
}
__device__ __forceinline__ void astorei(int* p, int v) {
    __hip_atomic_store(p, v, __ATOMIC_RELAXED, AGENT);
}

struct Ctrl {
    int first, target, roleCtr, open, mode, pad0, pad1, pad2;
    int xcds[96];
};

// ---------------- generic fp32 GEMM: C[m][n] = sum_k A[m][k]*B[n][k] + bias ----
template <bool LRELU>
__global__ __launch_bounds__(256) void gemm_bias(
    const float* __restrict__ A, const float* __restrict__ B,
    const float* __restrict__ bias1, const float* __restrict__ bias2,
    float* __restrict__ C, int M, int N, int K)
{
    __shared__ float As[16][68];
    __shared__ float Bs[16][68];
    const int tid = threadIdx.x;
    const int m0 = blockIdx.y * 64, n0 = blockIdx.x * 64;
    const int tm = tid >> 4, tn = tid & 15;
    const int lr = tid >> 2;
    const int lk = (tid & 3) * 4;
    float acc[4][4] = {};
    for (int k0 = 0; k0 < K; k0 += 16) {
        float4 av = make_float4(0.f, 0.f, 0.f, 0.f);
        if (m0 + lr < M) av = *(const float4*)&A[(size_t)(m0 + lr) * K + k0 + lk];
        As[lk + 0][lr] = av.x; As[lk + 1][lr] = av.y;
        As[lk + 2][lr] = av.z; As[lk + 3][lr] = av.w;
        float4 bv = make_float4(0.f, 0.f, 0.f, 0.f);
        if (n0 + lr < N) bv = *(const float4*)&B[(size_t)(n0 + lr) * K + k0 + lk];
        Bs[lk + 0][lr] = bv.x; Bs[lk + 1][lr] = bv.y;
        Bs[lk + 2][lr] = bv.z; Bs[lk + 3][lr] = bv.w;
        __syncthreads();
#pragma unroll
        for (int kk = 0; kk < 16; kk++) {
            float a[4], b[4];
#pragma unroll
            for (int i = 0; i < 4; i++) a[i] = As[kk][tm * 4 + i];
#pragma unroll
            for (int j = 0; j < 4; j++) b[j] = Bs[kk][tn * 4 + j];
#pragma unroll
            for (int i = 0; i < 4; i++)
#pragma unroll
                for (int j = 0; j < 4; j++) acc[i][j] += a[i] * b[j];
        }
        __syncthreads();
    }
#pragma unroll
    for (int i = 0; i < 4; i++) {
#pragma unroll
        for (int j = 0; j < 4; j++) {
            int mm = m0 + tm * 4 + i, nn = n0 + tn * 4 + j;
            if (mm < M && nn < N) {
                float v = acc[i][j];
                if (bias1) v += bias1[nn];
                if (bias2) v += bias2[nn];
                if (LRELU) v = lrelu(v);
                C[(size_t)mm * N + nn] = v;
            }
        }
    }
}

// ---------------- persistent pipelined LSTM1+LSTM2 scan ------------------------
// Tagged-data sync. mode==2: all 96 role-WGs verified on ONE XCD -> publish with
// sc0 stores AND poll with sc0 loads (matched XCC scope, shared-L2 coherence
// point). Producers additionally agent-store, and the fast poll is ADAPTIVE:
// after one 512-spin timeout the wave permanently falls back to agent polls, so
// a wrong scope theory costs ~50us once, not 2s.
__global__ __launch_bounds__(256) void lstm_pipe(
    const float* __restrict__ gx1, const float* __restrict__ Whh1,
    const float* __restrict__ Wih2, const float* __restrict__ Whh2,
    const float* __restrict__ bih2, const float* __restrict__ bhh2,
    u64* __restrict__ h1pub, u64* __restrict__ h2pub,
    float* __restrict__ h2seq, Ctrl* __restrict__ ctrl,
    u64* __restrict__ zerobuf)
{
    const int tid = threadIdx.x;
    __shared__ int sh_role, sh_mode, sh_first;

    // ---------------- XCD election ----------------
    if (tid == 0) {
        unsigned xcd;
        asm volatile("s_getreg_b32 %0, hwreg(HW_REG_XCC_ID)" : "=s"(xcd));
        xcd &= 15;
        int first = __hip_atomic_fetch_add(&ctrl->first, 1, __ATOMIC_RELAXED, AGENT);
        if (first == 0) astorei(&ctrl->target, (int)xcd | 256);
        int tgt;
        while (((tgt = aloadi(&ctrl->target)) & 256) == 0) {}
        tgt &= 255;
        u64 t0 = __builtin_amdgcn_s_memrealtime();
        int role = -1;
        if ((int)xcd == tgt) {
            role = __hip_atomic_fetch_add(&ctrl->roleCtr, 1, __ATOMIC_RELAXED, AGENT);
        } else {
            for (;;) {
                if (aloadi(&ctrl->roleCtr) >= 96) break;
                if (aloadi(&ctrl->open)) {
                    role = __hip_atomic_fetch_add(&ctrl->roleCtr, 1, __ATOMIC_RELAXED, AGENT);
                    break;
                }
            }
        }
        if (role >= 96) role = -1;
        if (role >= 0) astorei(&ctrl->xcds[role], (int)xcd + 1);
        if (first == 0) {
            while (aloadi(&ctrl->roleCtr) < 96) {
                if (__builtin_amdgcn_s_memrealtime() - t0 > 200000ull)
                    astorei(&ctrl->open, 1);
            }
        }
        sh_role = role; sh_first = first;
    }
    __syncthreads();
    {
        const int role_ = sh_role, first_ = sh_first;
        if (first_ == 0 && tid < 64) {
            int v0 = 0;
            if (tid == 0) { while ((v0 = aloadi(&ctrl->xcds[0])) == 0) {} }
            int ref = __shfl(v0, 0, 64);
            int a;
            while ((a = aloadi(&ctrl->xcds[tid])) == 0) {}
            bool ok = (a == ref);
            if (64 + tid < 96) {
                int b;
                while ((b = aloadi(&ctrl->xcds[64 + tid])) == 0) {}
                ok = ok && (b == ref);
            }
            int same = __all(ok);
            if (tid == 0) astorei(&ctrl->mode, same ? 2 : 1);
        }
        if (role_ < 0 && first_ != 0) return;  // WG-uniform
        if (tid == 0) {
            int m;
            while ((m = aloadi(&ctrl->mode)) == 0) {}
            sh_mode = m;
        }
        __syncthreads();
        if (sh_role < 0) return;
    }
    const int wg = sh_role;
    const int mode = sh_mode;

    const int r = tid & 31, p = tid >> 5;
    __shared__ float xl[512];
    __shared__ float hl[256];
    __shared__ float part[8][32];

    if (wg < 64) {
        // ---------------- LSTM1: H=512, owns h[jb..jb+8) ----------------
        const int jb = wg * 8;
        const int grow = (r >> 3) * 512 + jb + (r & 7);
        float w[64];
#pragma unroll
        for (int q = 0; q < 64; q++) w[q] = Whh1[(size_t)grow * 512 + p * 64 + q];
        float cstate = 0.f;
        bool fast = (mode == 2);

        for (int t = 0; t < 4096; ++t) {
            float gxv = 0.f;
            if (tid < 32) gxv = gx1[(size_t)t * 2048 + (tid >> 3) * 512 + jb + (tid & 7)];
            // poll h(t-1)
            const u64* p1 = (t > 0) ? (h1pub + (size_t)(t - 1) * 512 + 2 * tid)
                                    : (zerobuf + 2 * tid);
            const unsigned want = (unsigned)t;
            unsigned va = 0, vb = 0;
            bool got = false;
            if (fast) {
                uv4 v; int spins = 0;
                for (;;) {
                    asm volatile("global_load_dwordx4 %0, %1, off sc0\n\t"
                                 "s_waitcnt vmcnt(0)"
                                 : "=&v"(v) : "v"(p1) : "memory");
                    if (__all((v.y == want) & (v.w == want))) {
                        va = v.x; vb = v.z; got = true; break;
                    }
                    if (++spins > 512) { fast = false; break; }
                }
            }
            if (!got) {
                u64 a = aload64(p1), b = aload64(p1 + 1);
                while (!__all(((unsigned)(a >> 32) == want) &
                              ((unsigned)(b >> 32) == want))) {
                    if ((unsigned)(a >> 32) != want) a = aload64(p1);
                    if ((unsigned)(b >> 32) != want) b = aload64(p1 + 1);
                }
                va = (unsigned)a; vb = (unsigned)b;
            }
            xl[2 * tid] = __uint_as_float(va);
            xl[2 * tid + 1] = __uint_as_float(vb);
            __syncthreads();  // B1: xl ready
            float a0 = 0.f, a1 = 0.f, a2 = 0.f, a3 = 0.f;
            const float* xs = &xl[p * 64];
#pragma unroll
            for (int q = 0; q < 16; q++) {
                a0 += w[4 * q + 0] * xs[4 * q + 0];
                a1 += w[4 * q + 1] * xs[4 * q + 1];
                a2 += w[4 * q + 2] * xs[4 * q + 2];
                a3 += w[4 * q + 3] * xs[4 * q + 3];
            }
            part[p][r] = (a0 + a1) + (a2 + a3);
            __syncthreads();  // B2: partials ready
            if (tid < 32) {
                float s0 = gxv, s1 = 0.f;
#pragma unroll
                for (int pp = 0; pp < 4; pp++) {
                    s0 += part[2 * pp][tid];
                    s1 += part[2 * pp + 1][tid];
                }
                float s = s0 + s1;
                float act = ((tid >> 3) == 2) ? tanh_fast(s) : sigf(s);
                const int e = tid & 7;
                float vi = __shfl(act, e, 64);
                float vf = __shfl(act, e + 8, 64);
                float vg = __shfl(act, e + 16, 64);
                float vo = __shfl(act, e + 24, 64);
                if (tid < 8) {
                    float c = vf * cstate + vi * vg;
                    cstate = c;
                    float h = vo * tanh_fast(c);
                    u64* pp_ = h1pub + (size_t)t * 512 + jb + tid;
                    u64 pv = ((u64)(t + 1) << 32) | (u64)__float_as_uint(h);
                    if (mode == 2)
                        asm volatile("global_store_dwordx2 %0, %1, off sc0"
                                     :: "v"(pp_), "v"(pv) : "memory");
                    astore64(pp_, pv);
                }
            }
        }
    } else {
        // ---------------- LSTM2: H=256, pipelined 1 step behind ----------------
        const int k = wg - 64, jb = k * 8;
        const int grow = (r >> 3) * 256 + jb + (r & 7);
        float wi[64], wh[32];
#pragma unroll
        for (int q = 0; q < 64; q++) wi[q] = Wih2[(size_t)grow * 512 + p * 64 + q];
#pragma unroll
        for (int q = 0; q < 32; q++) wh[q] = Whh2[(size_t)grow * 256 + p * 32 + q];
        float bs = 0.f;
        if (tid < 32) {
            int row = (tid >> 3) * 256 + jb + (tid & 7);
            bs = bih2[row] + bhh2[row];
        }
        float cstate = 0.f;
        bool fast = (mode == 2);

        for (int t = 0; t < 4096; ++t) {
            {
                const u64* p1 = h1pub + (size_t)t * 512 + 2 * tid;
                const u64* p2 = (t > 0) ? (h2pub + (size_t)(t - 1) * 256 + tid)
                                        : (zerobuf + tid);
                const unsigned w1 = (unsigned)(t + 1), w2 = (unsigned)t;
                unsigned va = 0, vb = 0, vc = 0;
                bool got = false;
                if (fast) {
                    uv4 v; u64 c; int spins = 0;
                    for (;;) {
                        asm volatile("global_load_dwordx4 %0, %2, off sc0\n\t"
                                     "global_load_dwordx2 %1, %3, off sc0\n\t"
                                     "s_waitcnt vmcnt(0)"
                                     : "=&v"(v), "=&v"(c) : "v"(p1), "v"(p2) : "memory");
                        if (__all((v.y == w1) & (v.w == w1) &
                                  ((unsigned)(c >> 32) == w2))) {
                            va = v.x; vb = v.z; vc = (unsigned)c; got = true; break;
                        }
                        if (++spins > 512) { fast = false; break; }
                    }
                }
                if (!got) {
                    u64 a = aload64(p1), b = aload64(p1 + 1), c = aload64(p2);
                    while (!__all(((unsigned)(a >> 32) == w1) &
                                  ((unsigned)(b >> 32) == w1) &
                                  ((unsigned)(c >> 32) == w2))) {
                        if ((unsigned)(a >> 32) != w1) a = aload64(p1);
                        if ((unsigned)(b >> 32) != w1) b = aload64(p1 + 1);
                        if ((unsigned)(c >> 32) != w2) c = aload64(p2);
                    }
                    va = (unsigned)a; vb = (unsigned)b; vc = (unsigned)c;
                }
                xl[2 * tid] = lrelu(__uint_as_float(va));
                xl[2 * tid + 1] = lrelu(__uint_as_float(vb));
                hl[tid] = __uint_as_float(vc);
            }
            __syncthreads();  // B1
            float a0 = 0.f, a1 = 0.f, a2 = 0.f, a3 = 0.f;
            const float* xs = &xl[p * 64];
            const float* hs = &hl[p * 32];
#pragma unroll
            for (int q = 0; q < 16; q++) {
                a0 += wi[4 * q + 0] * xs[4 * q + 0];
                a1 += wi[4 * q + 1] * xs[4 * q + 1];
                a2 += wi[4 * q + 2] * xs[4 * q + 2];
                a3 += wi[4 * q + 3] * xs[4 * q + 3];
            }
#pragma unroll
            for (int q = 0; q < 8; q++) {
                a0 += wh[4 * q + 0] * hs[4 * q + 0];
                a1 += wh[4 * q + 1] * hs[4 * q + 1];
                a2 += wh[4 * q + 2] * hs[4 * q + 2];
                a3 += wh[4 * q + 3] * hs[4 * q + 3];
            }
            part[p][r] = (a0 + a1) + (a2 + a3);
            __syncthreads();  // B2
            if (tid < 32) {
                float s0 = bs, s1 = 0.f;
#pragma unroll
                for (int pp = 0; pp < 4; pp++) {
                    s0 += part[2 * pp][tid];
                    s1 += part[2 * pp + 1][tid];
                }
                float s = s0 + s1;
                float act = ((tid >> 3) == 2) ? tanh_fast(s) : sigf(s);
                const int e = tid & 7;
                float vi = __shfl(act, e, 64);
                float vf = __shfl(act, e + 8, 64);
                float vg = __shfl(act, e + 16, 64);
                float vo = __shfl(act, e + 24, 64);
                if (tid < 8) {
                    float c = vf * cstate + vi * vg;
                    cstate = c;
                    float h = vo * tanh_fast(c);
                    u64* pp_ = h2pub + (size_t)t * 256 + jb + tid;
                    u64 pv = ((u64)(t + 1) << 32) | (u64)__float_as_uint(h);
                    if (mode == 2)
                        asm volatile("global_store_dwordx2 %0, %1, off sc0"
                                     :: "v"(pp_), "v"(pv) : "memory");
                    astore64(pp_, pv);
                    h2seq[(size_t)t * 256 + jb + tid] = lrelu(h);
                }
            }
        }
    }
}

// ---------------- GCN edge scatter: y[dst] += ew * m[src] ----------------------
__global__ void gcn_scatter(const float* __restrict__ m, const int* __restrict__ ei,
                            const float* __restrict__ ew, float* __restrict__ y,
                            int shift, int nE)
{
    int idx = blockIdx.x * 256 + threadIdx.x;
    int e = idx >> shift;
    if (e >= nE) return;
    int C = 1 << shift;
    int ch = idx & (C - 1);
    int s = ei[e], d = ei[nE + e];
    atomicAdd(&y[(size_t)d * C + ch], ew[e] * m[(size_t)s * C + ch]);
}

// ---------------- BN (training-mode batch stats) -------------------------------
__global__ __launch_bounds__(256) void bn_stats(
    const float* __restrict__ x, const float* __restrict__ gamma,
    const float* __restrict__ beta, float* __restrict__ scale,
    float* __restrict__ shift, int Nn, int C)
{
    int ch = blockIdx.x;
    float s = 0.f, s2 = 0.f;
    for (int n = threadIdx.x; n < Nn; n += 256) {
        float v = x[(size_t)n * C + ch];
        s += v; s2 += v * v;
    }
    __shared__ float rs[256], rq[256];
    rs[threadIdx.x] = s; rq[threadIdx.x] = s2;
    __syncthreads();
    for (int o = 128; o > 0; o >>= 1) {
        if (threadIdx.x < o) {
            rs[threadIdx.x] += rs[threadIdx.x + o];
            rq[threadIdx.x] += rq[threadIdx.x + o];
        }
        __syncthreads();
    }
    if (threadIdx.x == 0) {
        float mean = rs[0] / Nn;
        float var = rq[0] / Nn - mean * mean;
        float inv = rsqrtf(var + 1e-5f);
        float sc = gamma[ch] * inv;
        scale[ch] = sc;
        shift[ch] = beta[ch] - mean * sc;
    }
}

__global__ void bn_apply(const float* __restrict__ x, const float* __restrict__ scale,
                         const float* __restrict__ shift, float* __restrict__ z,
                         int mask, int total)
{
    int idx = blockIdx.x * 256 + threadIdx.x;
    if (idx >= total) return;
    int ch = idx & mask;
    z[idx] = lrelu(x[idx] * scale[ch] + shift[ch]);
}

// ---------------- global_add_pool via batch array ------------------------------
__global__ void pool_kernel(const float* __restrict__ z, const int* __restrict__ batch,
                            float* __restrict__ pooled, int total)
{
    int idx = blockIdx.x * 256 + threadIdx.x;
    if (idx >= total) return;
    int n = idx >> 5, ch = idx & 31;
    atomicAdd(&pooled[(size_t)batch[n] * 32 + ch], z[idx]);
}

// ---------------- final tiny MLP: 32 -> 16 -> 8 -> 2, one thread per graph -----
__global__ void mlp_kernel(const float* __restrict__ pooled,
                           const float* __restrict__ w2, const float* __restrict__ b2,
                           const float* __restrict__ w3, const float* __restrict__ b3,
                           const float* __restrict__ w4, const float* __restrict__ b4,
                           float* __restrict__ out)
{
    int g = blockIdx.x * 256 + threadIdx.x;
    if (g >= 512) return;
    float pbuf[32];
#pragma unroll
    for (int i = 0; i < 32; i++) pbuf[i] = pooled[g * 32 + i];
    float a[16];
#pragma unroll
    for (int j = 0; j < 16; j++) {
        float s = b2[j];
#pragma unroll
        for (int i = 0; i < 32; i++) s += w2[j * 32 + i] * pbuf[i];
        a[j] = lrelu(s);
    }
    float c8[8];
#pragma unroll
    for (int j = 0; j < 8; j++) {
        float s = b3[j];
#pragma unroll
        for (int i = 0; i < 16; i++) s += w3[j * 16 + i] * a[i];
        c8[j] = lrelu(s);
    }
#pragma unroll
    for (int j = 0; j < 2; j++) {
        float s = b4[j];
#pragma unroll
        for (int i = 0; i < 8; i++) s += w4[j * 8 + i] * c8[i];
        out[g * 2 + j] = lrelu(s);
    }
}

extern "C" void kernel_launch(void* const* d_in, const int* in_sizes, int n_in,
                              void* d_out, int out_size, void* d_ws, size_t ws_size,
                              hipStream_t stream)
{
    (void)in_sizes; (void)n_in; (void)out_size; (void)ws_size;
    const float* x      = (const float*)d_in[0];
    const int*   ei     = (const int*)d_in[1];
    const float* ew     = (const float*)d_in[2];
    const int*   batch  = (const int*)d_in[3];
    const float* W_ih1  = (const float*)d_in[4];
    const float* W_hh1  = (const float*)d_in[5];
    const float* b_ih1  = (const float*)d_in[6];
    const float* b_hh1  = (const float*)d_in[7];
    const float* W_ih2  = (const float*)d_in[8];
    const float* W_hh2  = (const float*)d_in[9];
    const float* b_ih2  = (const float*)d_in[10];
    const float* b_hh2  = (const float*)d_in[11];
    const float* fc1_w  = (const float*)d_in[12];
    const float* fc1_b  = (const float*)d_in[13];
    const float* gcn1_w = (const float*)d_in[14];
    const float* bn1_g  = (const float*)d_in[16];
    const float* bn1_b  = (const float*)d_in[17];
    const float* gcn2_w = (const float*)d_in[18];
    const float* bn2_g  = (const float*)d_in[20];
    const float* bn2_b  = (const float*)d_in[21];
    const float* fc2_w  = (const float*)d_in[22];
    const float* fc2_b  = (const float*)d_in[23];
    const float* fc3_w  = (const float*)d_in[24];
    const float* fc3_b  = (const float*)d_in[25];
    const float* fc4_w  = (const float*)d_in[26];
    const float* fc4_b  = (const float*)d_in[27];
    float* out = (float*)d_out;

    // -------- workspace layout (byte offsets) --------
    char* base = (char*)d_ws;
    const size_t MB = 1024 * 1024;
    float* gx1    = (float*)base;                       // 32MB: 4096*2048 f32
    u64*   h1pub  = (u64*)(base + 32 * MB);             // 16MB: 4096*512 u64
    u64*   h2pub  = (u64*)(base + 48 * MB);             //  8MB: 4096*256 u64
    float* h2seq  = (float*)(base + 56 * MB);           //  4MB: 4096*256 f32
    float* scale1 = (float*)(base + 60 * MB);           // 64
    float* shift1 = scale1 + 64;                        // 64
    float* scale2 = shift1 + 64;                        // 32
    float* shift2 = scale2 + 32;                        // 32
    u64*   zerobuf = (u64*)(base + 60 * MB + 4096);     // 512 u64 (4KB), stays 0
    Ctrl*  ctrl   = (Ctrl*)(base + 60 * MB + 8192);     // election state
    // buffers used only AFTER lstm_pipe — aliased into gx1's space:
    float* h3     = (float*)base;                       // 4096*128
    float* m1     = h3 + (size_t)4096 * 128;            // 4096*64
    float* y1     = m1 + (size_t)4096 * 64;             // 4096*64 (bn in-place)
    float* m2     = y1 + (size_t)4096 * 64;             // 4096*32
    float* y2     = m2 + (size_t)4096 * 32;             // 4096*32 (bn in-place)
    float* pooled = y2 + (size_t)4096 * 32;             // 512*32

    dim3 b256(256);

    // fresh tags + election state every launch (no cross-call state)
    hipMemsetAsync(h1pub, 0, (size_t)4096 * 768 * sizeof(u64), stream);
    hipMemsetAsync(zerobuf, 0, 8192, stream);

    // gx1 = x @ W_ih1^T + (b_ih1 + b_hh1)   [4096,2048]
    gemm_bias<false><<<dim3(2048 / 64, 4096 / 64), b256, 0, stream>>>(
        x, W_ih1, b_ih1, b_hh1, gx1, 4096, 2048, 1280);

    // both LSTM scans, pipelined (96 persistent roles elected from 1024 WGs)
    lstm_pipe<<<1024, b256, 0, stream>>>(gx1, W_hh1, W_ih2, W_hh2, b_ih2, b_hh2,
                                         h1pub, h2pub, h2seq, ctrl, zerobuf);

    // fc1 + lrelu  [4096,128]
    gemm_bias<true><<<dim3(128 / 64, 4096 / 64), b256, 0, stream>>>(
        h2seq, fc1_w, fc1_b, nullptr, h3, 4096, 128, 256);

    // gcn1 linear [4096,64]  (bias cancels in BN)
    gemm_bias<false><<<dim3(1, 4096 / 64), b256, 0, stream>>>(
        h3, gcn1_w, nullptr, nullptr, m1, 4096, 64, 128);
    hipMemsetAsync(y1, 0, (size_t)4096 * 64 * sizeof(float), stream);
    gcn_scatter<<<(32768 * 64) / 256, b256, 0, stream>>>(m1, ei, ew, y1, 6, 32768);
    bn_stats<<<64, b256, 0, stream>>>(y1, bn1_g, bn1_b, scale1, shift1, 4096, 64);
    bn_apply<<<(4096 * 64) / 256, b256, 0, stream>>>(y1, scale1, shift1, y1, 63, 4096 * 64);

    // gcn2 linear [4096,32]
    gemm_bias<false><<<dim3(1, 4096 / 64), b256, 0, stream>>>(
        y1, gcn2_w, nullptr, nullptr, m2, 4096, 32, 64);
    hipMemsetAsync(y2, 0, (size_t)4096 * 32 * sizeof(float), stream);
    gcn_scatter<<<(32768 * 32) / 256, b256, 0, stream>>>(m2, ei, ew, y2, 5, 32768);
    bn_stats<<<32, b256, 0, stream>>>(y2, bn2_g, bn2_b, scale2, shift2, 4096, 32);
    bn_apply<<<(4096 * 32) / 256, b256, 0, stream>>>(y2, scale2, shift2, y2, 31, 4096 * 32);

    // pool + MLP head
    hipMemsetAsync(pooled, 0, (size_t)512 * 32 * sizeof(float), stream);
    pool_kernel<<<(4096 * 32) / 256, b256, 0, stream>>>(y2, batch, pooled, 4096 * 32);
    mlp_kernel<<<2, b256, 0, stream>>>(pooled, fc2_w, fc2_b, fc3_w, fc3_b,
                                       fc4_w, fc4_b, out);
}

// Round 7
// 11975.658 us; speedup vs baseline: 179.5836x; 1.0513x over previous
//
#include <hip/hip_runtime.h>
#include <math.h>

#define AGENT __HIP_MEMORY_SCOPE_AGENT
typedef unsigned long long u64;
typedef unsigned int uv4 __attribute__((ext_vector_type(4)));

__device__ __forceinline__ float sigf(float x) { return 1.f / (1.f + __expf(-x)); }
__device__ __forceinline__ float tanh_fast(float x) { return 1.f - 2.f / (__expf(2.f * x) + 1.f); }
__device__ __forceinline__ float lrelu(float x) { return x > 0.f ? x : 0.01f * x; }
__device__ __forceinline__ u64 aload64(const u64* p) {
    return __hip_atomic_load(p, __ATOMIC_RELAXED, AGENT);
}
__device__ __forceinline__ void astore64(u64* p, u64 v) {
    __hip_atomic_store(p, v, __ATOMIC_RELAXED, AGENT);
}
__device__ __forceinline__ int aloadi(const int* p) {
    return __hip_atomic_load(p, __ATOMIC_RELAXED, AGENT);
}
__device__ __forceinline__ void astorei(int* p, int v) {
    __hip_atomic_store(p, v, __ATOMIC_RELAXED, AGENT);
}

struct Ctrl {
    int first, target, roleCtr, open, mode, pad0, pad1, pad2;
    int xcds[96];
};

// ---------------- generic fp32 GEMM: C[m][n] = sum_k A[m][k]*B[n][k] + bias ----
template <bool LRELU>
__global__ __launch_bounds__(256) void gemm_bias(
    const float* __restrict__ A, const float* __restrict__ B,
    const float* __restrict__ bias1, const float* __restrict__ bias2,
    float* __restrict__ C, int M, int N, int K)
{
    __shared__ float As[16][68];
    __shared__ float Bs[16][68];
    const int tid = threadIdx.x;
    const int m0 = blockIdx.y * 64, n0 = blockIdx.x * 64;
    const int tm = tid >> 4, tn = tid & 15;
    const int lr = tid >> 2;
    const int lk = (tid & 3) * 4;
    float acc[4][4] = {};
    for (int k0 = 0; k0 < K; k0 += 16) {
        float4 av = make_float4(0.f, 0.f, 0.f, 0.f);
        if (m0 + lr < M) av = *(const float4*)&A[(size_t)(m0 + lr) * K + k0 + lk];
        As[lk + 0][lr] = av.x; As[lk + 1][lr] = av.y;
        As[lk + 2][lr] = av.z; As[lk + 3][lr] = av.w;
        float4 bv = make_float4(0.f, 0.f, 0.f, 0.f);
        if (n0 + lr < N) bv = *(const float4*)&B[(size_t)(n0 + lr) * K + k0 + lk];
        Bs[lk + 0][lr] = bv.x; Bs[lk + 1][lr] = bv.y;
        Bs[lk + 2][lr] = bv.z; Bs[lk + 3][lr] = bv.w;
        __syncthreads();
#pragma unroll
        for (int kk = 0; kk < 16; kk++) {
            float a[4], b[4];
#pragma unroll
            for (int i = 0; i < 4; i++) a[i] = As[kk][tm * 4 + i];
#pragma unroll
            for (int j = 0; j < 4; j++) b[j] = Bs[kk][tn * 4 + j];
#pragma unroll
            for (int i = 0; i < 4; i++)
#pragma unroll
                for (int j = 0; j < 4; j++) acc[i][j] += a[i] * b[j];
        }
        __syncthreads();
    }
#pragma unroll
    for (int i = 0; i < 4; i++) {
#pragma unroll
        for (int j = 0; j < 4; j++) {
            int mm = m0 + tm * 4 + i, nn = n0 + tn * 4 + j;
            if (mm < M && nn < N) {
                float v = acc[i][j];
                if (bias1) v += bias1[nn];
                if (bias2) v += bias2[nn];
                if (LRELU) v = lrelu(v);
                C[(size_t)mm * N + nn] = v;
            }
        }
    }
}

// ---------------- persistent pipelined LSTM1+LSTM2 scan ------------------------
// Tagged-data sync, TWO disjoint publication buffers:
//   *fast : written ONLY with sc0 stores (mode 2), polled with sc0 loads —
//           pure XCC-scope experiment, cannot contaminate the slow path.
//   *slow : ALWAYS written with agent stores, polled with agent loads —
//           guaranteed-progress path (R3 behavior).
// Consumers try fast (512-spin, once per wave), then permanently use slow.
__global__ __launch_bounds__(256) void lstm_pipe(
    const float* __restrict__ gx1, const float* __restrict__ Whh1,
    const float* __restrict__ Wih2, const float* __restrict__ Whh2,
    const float* __restrict__ bih2, const float* __restrict__ bhh2,
    u64* __restrict__ h1fast, u64* __restrict__ h1slow,
    u64* __restrict__ h2fast, u64* __restrict__ h2slow,
    float* __restrict__ h2seq, Ctrl* __restrict__ ctrl,
    u64* __restrict__ zerobuf, int allow_fast)
{
    const int tid = threadIdx.x;
    __shared__ int sh_role, sh_mode, sh_first;

    // ---------------- XCD election ----------------
    if (tid == 0) {
        unsigned xcd;
        asm volatile("s_getreg_b32 %0, hwreg(HW_REG_XCC_ID)" : "=s"(xcd));
        xcd &= 15;
        int first = __hip_atomic_fetch_add(&ctrl->first, 1, __ATOMIC_RELAXED, AGENT);
        if (first == 0) astorei(&ctrl->target, (int)xcd | 256);
        int tgt;
        while (((tgt = aloadi(&ctrl->target)) & 256) == 0) {}
        tgt &= 255;
        u64 t0 = __builtin_amdgcn_s_memrealtime();
        int role = -1;
        if ((int)xcd == tgt) {
            role = __hip_atomic_fetch_add(&ctrl->roleCtr, 1, __ATOMIC_RELAXED, AGENT);
        } else {
            for (;;) {
                if (aloadi(&ctrl->roleCtr) >= 96) break;
                if (aloadi(&ctrl->open)) {
                    role = __hip_atomic_fetch_add(&ctrl->roleCtr, 1, __ATOMIC_RELAXED, AGENT);
                    break;
                }
            }
        }
        if (role >= 96) role = -1;
        if (role >= 0) astorei(&ctrl->xcds[role], (int)xcd + 1);
        if (first == 0) {
            while (aloadi(&ctrl->roleCtr) < 96) {
                if (__builtin_amdgcn_s_memrealtime() - t0 > 200000ull)
                    astorei(&ctrl->open, 1);
            }
        }
        sh_role = role; sh_first = first;
    }
    __syncthreads();
    {
        const int role_ = sh_role, first_ = sh_first;
        if (first_ == 0 && tid < 64) {
            int v0 = 0;
            if (tid == 0) { while ((v0 = aloadi(&ctrl->xcds[0])) == 0) {} }
            int ref = __shfl(v0, 0, 64);
            int a;
            while ((a = aloadi(&ctrl->xcds[tid])) == 0) {}
            bool ok = (a == ref);
            if (64 + tid < 96) {
                int b;
                while ((b = aloadi(&ctrl->xcds[64 + tid])) == 0) {}
                ok = ok && (b == ref);
            }
            int same = __all(ok);
            if (tid == 0) astorei(&ctrl->mode, (same && allow_fast) ? 2 : 1);
        }
        if (role_ < 0 && first_ != 0) return;  // WG-uniform
        if (tid == 0) {
            int m;
            while ((m = aloadi(&ctrl->mode)) == 0) {}
            sh_mode = m;
        }
        __syncthreads();
        if (sh_role < 0) return;
    }
    const int wg = sh_role;
    const int mode = sh_mode;

    const int r = tid & 31, p = tid >> 5;
    __shared__ float xl[512];
    __shared__ float hl[256];
    __shared__ float part[8][32];

    if (wg < 64) {
        // ---------------- LSTM1: H=512, owns h[jb..jb+8) ----------------
        const int jb = wg * 8;
        const int grow = (r >> 3) * 512 + jb + (r & 7);
        float w[64];
#pragma unroll
        for (int q = 0; q < 64; q++) w[q] = Whh1[(size_t)grow * 512 + p * 64 + q];
        float cstate = 0.f;
        bool fast = (mode == 2);

        for (int t = 0; t < 4096; ++t) {
            // prefetch gx for this step's 32 gate rows (independent of poll)
            float gxv = 0.f;
            if (tid < 32) gxv = gx1[(size_t)t * 2048 + (tid >> 3) * 512 + jb + (tid & 7)];
            // poll h(t-1)
            const u64* pf = (t > 0) ? (h1fast + (size_t)(t - 1) * 512 + 2 * tid)
                                    : (zerobuf + 2 * tid);
            const u64* ps = (t > 0) ? (h1slow + (size_t)(t - 1) * 512 + 2 * tid)
                                    : (zerobuf + 2 * tid);
            const unsigned want = (unsigned)t;
            unsigned va = 0, vb = 0;
            bool got = false;
            if (fast) {
                uv4 v; int spins = 0;
                for (;;) {
                    asm volatile("global_load_dwordx4 %0, %1, off sc0\n\t"
                                 "s_waitcnt vmcnt(0)"
                                 : "=&v"(v) : "v"(pf) : "memory");
                    if (__all((v.y == want) & (v.w == want))) {
                        va = v.x; vb = v.z; got = true; break;
                    }
                    if (++spins > 512) { fast = false; break; }
                }
            }
            if (!got) {
                u64 a = aload64(ps), b = aload64(ps + 1);
                while (!__all(((unsigned)(a >> 32) == want) &
                              ((unsigned)(b >> 32) == want))) {
                    if ((unsigned)(a >> 32) != want) a = aload64(ps);
                    if ((unsigned)(b >> 32) != want) b = aload64(ps + 1);
                }
                va = (unsigned)a; vb = (unsigned)b;
            }
            xl[2 * tid] = __uint_as_float(va);
            xl[2 * tid + 1] = __uint_as_float(vb);
            __syncthreads();  // B1: xl ready
            float acc = 0.f;
#pragma unroll
            for (int q = 0; q < 64; q++) acc += w[q] * xl[p * 64 + q];
            part[p][r] = acc;
            __syncthreads();  // B2: partials ready
            if (tid < 32) {
                float s = gxv;
#pragma unroll
                for (int pp = 0; pp < 8; pp++) s += part[pp][tid];
                float act = ((tid >> 3) == 2) ? tanh_fast(s) : sigf(s);
                const int e = tid & 7;
                float vi = __shfl(act, e, 64);
                float vf = __shfl(act, e + 8, 64);
                float vg = __shfl(act, e + 16, 64);
                float vo = __shfl(act, e + 24, 64);
                if (tid < 8) {
                    float c = vf * cstate + vi * vg;
                    cstate = c;
                    float h = vo * tanh_fast(c);
                    u64 pv = ((u64)(t + 1) << 32) | (u64)__float_as_uint(h);
                    const size_t ofs = (size_t)t * 512 + jb + tid;
                    if (mode == 2) {
                        u64* pfw = h1fast + ofs;
                        asm volatile("global_store_dwordx2 %0, %1, off sc0"
                                     :: "v"(pfw), "v"(pv) : "memory");
                    }
                    astore64(h1slow + ofs, pv);
                }
            }
        }
    } else {
        // ---------------- LSTM2: H=256, pipelined 1 step behind ----------------
        const int k = wg - 64, jb = k * 8;
        const int grow = (r >> 3) * 256 + jb + (r & 7);
        float wi[64], wh[32];
#pragma unroll
        for (int q = 0; q < 64; q++) wi[q] = Wih2[(size_t)grow * 512 + p * 64 + q];
#pragma unroll
        for (int q = 0; q < 32; q++) wh[q] = Whh2[(size_t)grow * 256 + p * 32 + q];
        float bs = 0.f;
        if (tid < 32) {
            int row = (tid >> 3) * 256 + jb + (tid & 7);
            bs = bih2[row] + bhh2[row];
        }
        float cstate = 0.f;
        bool fast = (mode == 2);

        for (int t = 0; t < 4096; ++t) {
            {
                const u64* pf1 = h1fast + (size_t)t * 512 + 2 * tid;
                const u64* ps1 = h1slow + (size_t)t * 512 + 2 * tid;
                const u64* pf2 = (t > 0) ? (h2fast + (size_t)(t - 1) * 256 + tid)
                                         : (zerobuf + tid);
                const u64* ps2 = (t > 0) ? (h2slow + (size_t)(t - 1) * 256 + tid)
                                         : (zerobuf + tid);
                const unsigned w1 = (unsigned)(t + 1), w2 = (unsigned)t;
                unsigned va = 0, vb = 0, vc = 0;
                bool got = false;
                if (fast) {
                    uv4 v; u64 c; int spins = 0;
                    for (;;) {
                        asm volatile("global_load_dwordx4 %0, %2, off sc0\n\t"
                                     "global_load_dwordx2 %1, %3, off sc0\n\t"
                                     "s_waitcnt vmcnt(0)"
                                     : "=&v"(v), "=&v"(c) : "v"(pf1), "v"(pf2) : "memory");
                        if (__all((v.y == w1) & (v.w == w1) &
                                  ((unsigned)(c >> 32) == w2))) {
                            va = v.x; vb = v.z; vc = (unsigned)c; got = true; break;
                        }
                        if (++spins > 512) { fast = false; break; }
                    }
                }
                if (!got) {
                    u64 a = aload64(ps1), b = aload64(ps1 + 1), c = aload64(ps2);
                    while (!__all(((unsigned)(a >> 32) == w1) &
                                  ((unsigned)(b >> 32) == w1) &
                                  ((unsigned)(c >> 32) == w2))) {
                        if ((unsigned)(a >> 32) != w1) a = aload64(ps1);
                        if ((unsigned)(b >> 32) != w1) b = aload64(ps1 + 1);
                        if ((unsigned)(c >> 32) != w2) c = aload64(ps2);
                    }
                    va = (unsigned)a; vb = (unsigned)b; vc = (unsigned)c;
                }
                xl[2 * tid] = lrelu(__uint_as_float(va));
                xl[2 * tid + 1] = lrelu(__uint_as_float(vb));
                hl[tid] = __uint_as_float(vc);
            }
            __syncthreads();  // B1
            float acc = 0.f;
#pragma unroll
            for (int q = 0; q < 64; q++) acc += wi[q] * xl[p * 64 + q];
#pragma unroll
            for (int q = 0; q < 32; q++) acc += wh[q] * hl[p * 32 + q];
            part[p][r] = acc;
            __syncthreads();  // B2
            if (tid < 32) {
                float s = bs;
#pragma unroll
                for (int pp = 0; pp < 8; pp++) s += part[pp][tid];
                float act = ((tid >> 3) == 2) ? tanh_fast(s) : sigf(s);
                const int e = tid & 7;
                float vi = __shfl(act, e, 64);
                float vf = __shfl(act, e + 8, 64);
                float vg = __shfl(act, e + 16, 64);
                float vo = __shfl(act, e + 24, 64);
                if (tid < 8) {
                    float c = vf * cstate + vi * vg;
                    cstate = c;
                    float h = vo * tanh_fast(c);
                    u64 pv = ((u64)(t + 1) << 32) | (u64)__float_as_uint(h);
                    const size_t ofs = (size_t)t * 256 + jb + tid;
                    if (mode == 2) {
                        u64* pfw = h2fast + ofs;
                        asm volatile("global_store_dwordx2 %0, %1, off sc0"
                                     :: "v"(pfw), "v"(pv) : "memory");
                    }
                    astore64(h2slow + ofs, pv);
                    h2seq[ofs] = lrelu(h);
                }
            }
        }
    }
}

// ---------------- GCN edge scatter: y[dst] += ew * m[src] ----------------------
__global__ void gcn_scatter(const float* __restrict__ m, const int* __restrict__ ei,
                            const float* __restrict__ ew, float* __restrict__ y,
                            int shift, int nE)
{
    int idx = blockIdx.x * 256 + threadIdx.x;
    int e = idx >> shift;
    if (e >= nE) return;
    int C = 1 << shift;
    int ch = idx & (C - 1);
    int s = ei[e], d = ei[nE + e];
    atomicAdd(&y[(size_t)d * C + ch], ew[e] * m[(size_t)s * C + ch]);
}

// ---------------- BN (training-mode batch stats) -------------------------------
__global__ __launch_bounds__(256) void bn_stats(
    const float* __restrict__ x, const float* __restrict__ gamma,
    const float* __restrict__ beta, float* __restrict__ scale,
    float* __restrict__ shift, int Nn, int C)
{
    int ch = blockIdx.x;
    float s = 0.f, s2 = 0.f;
    for (int n = threadIdx.x; n < Nn; n += 256) {
        float v = x[(size_t)n * C + ch];
        s += v; s2 += v * v;
    }
    __shared__ float rs[256], rq[256];
    rs[threadIdx.x] = s; rq[threadIdx.x] = s2;
    __syncthreads();
    for (int o = 128; o > 0; o >>= 1) {
        if (threadIdx.x < o) {
            rs[threadIdx.x] += rs[threadIdx.x + o];
            rq[threadIdx.x] += rq[threadIdx.x + o];
        }
        __syncthreads();
    }
    if (threadIdx.x == 0) {
        float mean = rs[0] / Nn;
        float var = rq[0] / Nn - mean * mean;
        float inv = rsqrtf(var + 1e-5f);
        float sc = gamma[ch] * inv;
        scale[ch] = sc;
        shift[ch] = beta[ch] - mean * sc;
    }
}

__global__ void bn_apply(const float* __restrict__ x, const float* __restrict__ scale,
                         const float* __restrict__ shift, float* __restrict__ z,
                         int mask, int total)
{
    int idx = blockIdx.x * 256 + threadIdx.x;
    if (idx >= total) return;
    int ch = idx & mask;
    z[idx] = lrelu(x[idx] * scale[ch] + shift[ch]);
}

// ---------------- global_add_pool via batch array ------------------------------
__global__ void pool_kernel(const float* __restrict__ z, const int* __restrict__ batch,
                            float* __restrict__ pooled, int total)
{
    int idx = blockIdx.x * 256 + threadIdx.x;
    if (idx >= total) return;
    int n = idx >> 5, ch = idx & 31;
    atomicAdd(&pooled[(size_t)batch[n] * 32 + ch], z[idx]);
}

// ---------------- final tiny MLP: 32 -> 16 -> 8 -> 2, one thread per graph -----
__global__ void mlp_kernel(const float* __restrict__ pooled,
                           const float* __restrict__ w2, const float* __restrict__ b2,
                           const float* __restrict__ w3, const float* __restrict__ b3,
                           const float* __restrict__ w4, const float* __restrict__ b4,
                           float* __restrict__ out)
{
    int g = blockIdx.x * 256 + threadIdx.x;
    if (g >= 512) return;
    float pbuf[32];
#pragma unroll
    for (int i = 0; i < 32; i++) pbuf[i] = pooled[g * 32 + i];
    float a[16];
#pragma unroll
    for (int j = 0; j < 16; j++) {
        float s = b2[j];
#pragma unroll
        for (int i = 0; i < 32; i++) s += w2[j * 32 + i] * pbuf[i];
        a[j] = lrelu(s);
    }
    float c8[8];
#pragma unroll
    for (int j = 0; j < 8; j++) {
        float s = b3[j];
#pragma unroll
        for (int i = 0; i < 16; i++) s += w3[j * 16 + i] * a[i];
        c8[j] = lrelu(s);
    }
#pragma unroll
    for (int j = 0; j < 2; j++) {
        float s = b4[j];
#pragma unroll
        for (int i = 0; i < 8; i++) s += w4[j * 8 + i] * c8[i];
        out[g * 2 + j] = lrelu(s);
    }
}

extern "C" void kernel_launch(void* const* d_in, const int* in_sizes, int n_in,
                              void* d_out, int out_size, void* d_ws, size_t ws_size,
                              hipStream_t stream)
{
    (void)in_sizes; (void)n_in; (void)out_size;
    const float* x      = (const float*)d_in[0];
    const int*   ei     = (const int*)d_in[1];
    const float* ew     = (const float*)d_in[2];
    const int*   batch  = (const int*)d_in[3];
    const float* W_ih1  = (const float*)d_in[4];
    const float* W_hh1  = (const float*)d_in[5];
    const float* b_ih1  = (const float*)d_in[6];
    const float* b_hh1  = (const float*)d_in[7];
    const float* W_ih2  = (const float*)d_in[8];
    const float* W_hh2  = (const float*)d_in[9];
    const float* b_ih2  = (const float*)d_in[10];
    const float* b_hh2  = (const float*)d_in[11];
    const float* fc1_w  = (const float*)d_in[12];
    const float* fc1_b  = (const float*)d_in[13];
    const float* gcn1_w = (const float*)d_in[14];
    const float* bn1_g  = (const float*)d_in[16];
    const float* bn1_b  = (const float*)d_in[17];
    const float* gcn2_w = (const float*)d_in[18];
    const float* bn2_g  = (const float*)d_in[20];
    const float* bn2_b  = (const float*)d_in[21];
    const float* fc2_w  = (const float*)d_in[22];
    const float* fc2_b  = (const float*)d_in[23];
    const float* fc3_w  = (const float*)d_in[24];
    const float* fc3_b  = (const float*)d_in[25];
    const float* fc4_w  = (const float*)d_in[26];
    const float* fc4_b  = (const float*)d_in[27];
    float* out = (float*)d_out;

    // -------- workspace layout (byte offsets) --------
    char* base = (char*)d_ws;
    const size_t MB = 1024 * 1024;
    float* gx1    = (float*)base;                       // 32MB: 4096*2048 f32
    u64*   h1slow = (u64*)(base + 32 * MB);             // 16MB
    u64*   h2slow = (u64*)(base + 48 * MB);             //  8MB
    float* h2seq  = (float*)(base + 56 * MB);           //  4MB
    float* scale1 = (float*)(base + 60 * MB);           // 64
    float* shift1 = scale1 + 64;                        // 64
    float* scale2 = shift1 + 64;                        // 32
    float* shift2 = scale2 + 32;                        // 32
    u64*   zerobuf = (u64*)(base + 60 * MB + 4096);     // 4KB, stays 0
    Ctrl*  ctrl   = (Ctrl*)(base + 60 * MB + 8192);     // election state
    u64*   h1fast = (u64*)(base + 61 * MB);             // 16MB
    u64*   h2fast = (u64*)(base + 77 * MB);             //  8MB
    const int allow_fast = (ws_size >= 85 * MB) ? 1 : 0;
    if (!allow_fast) { h1fast = h1slow; h2fast = h2slow; }
    // buffers used only AFTER lstm_pipe — aliased into gx1's space:
    float* h3     = (float*)base;                       // 4096*128
    float* m1     = h3 + (size_t)4096 * 128;            // 4096*64
    float* y1     = m1 + (size_t)4096 * 64;             // 4096*64 (bn in-place)
    float* m2     = y1 + (size_t)4096 * 64;             // 4096*32
    float* y2     = m2 + (size_t)4096 * 32;             // 4096*32 (bn in-place)
    float* pooled = y2 + (size_t)4096 * 32;             // 512*32

    dim3 b256(256);

    // fresh tags + election state every launch (no cross-call state)
    hipMemsetAsync(h1slow, 0, (size_t)24 * MB, stream);           // h1slow+h2slow
    hipMemsetAsync(zerobuf, 0, 8192, stream);                     // zerobuf+ctrl
    if (allow_fast) hipMemsetAsync(h1fast, 0, (size_t)24 * MB, stream);

    // gx1 = x @ W_ih1^T + (b_ih1 + b_hh1)   [4096,2048]
    gemm_bias<false><<<dim3(2048 / 64, 4096 / 64), b256, 0, stream>>>(
        x, W_ih1, b_ih1, b_hh1, gx1, 4096, 2048, 1280);

    // both LSTM scans, pipelined (96 persistent roles elected from 1024 WGs)
    lstm_pipe<<<1024, b256, 0, stream>>>(gx1, W_hh1, W_ih2, W_hh2, b_ih2, b_hh2,
                                         h1fast, h1slow, h2fast, h2slow,
                                         h2seq, ctrl, zerobuf, allow_fast);

    // fc1 + lrelu  [4096,128]
    gemm_bias<true><<<dim3(128 / 64, 4096 / 64), b256, 0, stream>>>(
        h2seq, fc1_w, fc1_b, nullptr, h3, 4096, 128, 256);

    // gcn1 linear [4096,64]  (bias cancels in BN)
    gemm_bias<false><<<dim3(1, 4096 / 64), b256, 0, stream>>>(
        h3, gcn1_w, nullptr, nullptr, m1, 4096, 64, 128);
    hipMemsetAsync(y1, 0, (size_t)4096 * 64 * sizeof(float), stream);
    gcn_scatter<<<(32768 * 64) / 256, b256, 0, stream>>>(m1, ei, ew, y1, 6, 32768);
    bn_stats<<<64, b256, 0, stream>>>(y1, bn1_g, bn1_b, scale1, shift1, 4096, 64);
    bn_apply<<<(4096 * 64) / 256, b256, 0, stream>>>(y1, scale1, shift1, y1, 63, 4096 * 64);

    // gcn2 linear [4096,32]
    gemm_bias<false><<<dim3(1, 4096 / 64), b256, 0, stream>>>(
        y1, gcn2_w, nullptr, nullptr, m2, 4096, 32, 64);
    hipMemsetAsync(y2, 0, (size_t)4096 * 32 * sizeof(float), stream);
    gcn_scatter<<<(32768 * 32) / 256, b256, 0, stream>>>(m2, ei, ew, y2, 5, 32768);
    bn_stats<<<32, b256, 0, stream>>>(y2, bn2_g, bn2_b, scale2, shift2, 4096, 32);
    bn_apply<<<(4096 * 32) / 256, b256, 0, stream>>>(y2, scale2, shift2, y2, 31, 4096 * 32);

    // pool + MLP head
    hipMemsetAsync(pooled, 0, (size_t)512 * 32 * sizeof(float), stream);
    pool_kernel<<<(4096 * 32) / 256, b256, 0, stream>>>(y2, batch, pooled, 4096 * 32);
    mlp_kernel<<<2, b256, 0, stream>>>(pooled, fc2_w, fc2_b, fc3_w, fc3_b,
                                       fc4_w, fc4_b, out);
}